// Round 10
// baseline (379.748 us; speedup 1.0000x reference)
//
#include <hip/hip_runtime.h>
#include <hip/hip_bf16.h>

#define NN 50000
#define NE 800000
#define NB 196          // ceil(NN/256)

#define TW_BLOCKS   192     // 8*8*3
#define HIST_BLOCKS 3125    // ceil(NE/256)
#define SCAT_BLOCKS 3125
#define GEMM_RB     782     // 50048/64 row-blocks (64 rows per block)
#define GEMM_BLOCKS (GEMM_RB * 6)

#if __has_builtin(__builtin_amdgcn_cvt_pk_fp8_f32) && __has_builtin(__builtin_amdgcn_cvt_pk_f32_fp8)
#define HAVE_FP8 1
#define ROWB 768            // 256B fp8 Wh | 512B bf16 Vh
#else
#define HAVE_FP8 0
#define ROWB 1024           // 512B bf16 Wh | 512B bf16 Vh
#endif

typedef __attribute__((ext_vector_type(8))) short short8;
typedef __attribute__((ext_vector_type(4))) float floatx4;
typedef __attribute__((ext_vector_type(2))) float floatx2;
typedef unsigned short u16;
typedef unsigned int u32;

__device__ __forceinline__ u16 f2bf(float f) {
    u32 u = __float_as_uint(f);
    u += 0x7FFFu + ((u >> 16) & 1u);   // RNE
    return (u16)(u >> 16);
}
__device__ __forceinline__ float bf_lo(u32 u) { return __uint_as_float(u << 16); }
__device__ __forceinline__ float bf_hi(u32 u) { return __uint_as_float(u & 0xFFFF0000u); }
__device__ __forceinline__ u32 pack_bf(float lo, float hi) {
    return (u32)f2bf(lo) | ((u32)f2bf(hi) << 16);
}

#if __has_builtin(__builtin_amdgcn_exp2f)
#define EXP2F(x) __builtin_amdgcn_exp2f(x)
#else
#define EXP2F(x) exp2f(x)
#endif

// =============== prep: W/U/V transpose + degree histogram ===============
__global__ __launch_bounds__(256) void prep_kernel(
    const float* __restrict__ W, const float* __restrict__ U, const float* __restrict__ V,
    u16* __restrict__ wT, const int* __restrict__ dst, int* __restrict__ deg) {
    __shared__ float s[32][33];
    int b = blockIdx.x;
    if (b < TW_BLOCKS) {
        int g = b >> 6, rem = b & 63;
        int r0 = (rem & 7) * 32, c0 = (rem >> 3) * 32;
        const float* M = (g == 0) ? W : ((g == 1) ? U : V);
        int tx = threadIdx.x & 31, ty = threadIdx.x >> 5;   // 32 x 8
#pragma unroll
        for (int k = 0; k < 4; ++k)
            s[ty + k * 8][tx] = M[(size_t)(r0 + ty + k * 8) * 256 + c0 + tx];
        __syncthreads();
#pragma unroll
        for (int k = 0; k < 4; ++k)
            wT[(size_t)(g * 256 + c0 + ty + k * 8) * 256 + r0 + tx] = f2bf(s[tx][ty + k * 8]);
    } else {
        int e = (b - TW_BLOCKS) * 256 + threadIdx.x;
        if (e < NE) atomicAdd(&deg[dst[e]], 1);
    }
}

// ---------------- 3-phase scan ----------------
__global__ __launch_bounds__(256) void scanA_kernel(const int* __restrict__ deg, int* __restrict__ bsum) {
    int t = threadIdx.x;
    int i = blockIdx.x * 256 + t;
    int v = (i < NN) ? deg[i] : 0;
#pragma unroll
    for (int m = 32; m; m >>= 1) v += __shfl_xor(v, m, 64);
    __shared__ int ws[4];
    if ((t & 63) == 0) ws[t >> 6] = v;
    __syncthreads();
    if (t == 0) bsum[blockIdx.x] = ws[0] + ws[1] + ws[2] + ws[3];
}

__global__ __launch_bounds__(256) void scanB_kernel(const int* __restrict__ bsum, int* __restrict__ bpre,
                                                    int* __restrict__ rows_end) {
    int t = threadIdx.x, lane = t & 63, wv = t >> 6;
    int v = (t < NB) ? bsum[t] : 0;
    int inc = v;
#pragma unroll
    for (int off = 1; off < 64; off <<= 1) {
        int u = __shfl_up(inc, off, 64);
        if (lane >= off) inc += u;
    }
    __shared__ int wsum[4];
    if (lane == 63) wsum[wv] = inc;
    __syncthreads();
    int woff = 0;
    for (int k = 0; k < wv; ++k) woff += wsum[k];
    if (t < NB) bpre[t] = woff + inc - v;
    if (t == 255) rows_end[0] = woff + inc;
}

__global__ __launch_bounds__(256) void scanC_kernel(const int* __restrict__ deg, const int* __restrict__ bpre,
                                                    int* __restrict__ rows, int* __restrict__ cursor) {
    int t = threadIdx.x, lane = t & 63, wv = t >> 6;
    int i = blockIdx.x * 256 + t;
    int v = (i < NN) ? deg[i] : 0;
    int inc = v;
#pragma unroll
    for (int off = 1; off < 64; off <<= 1) {
        int u = __shfl_up(inc, off, 64);
        if (lane >= off) inc += u;
    }
    __shared__ int wsum[4];
    if (lane == 63) wsum[wv] = inc;
    __syncthreads();
    int woff = bpre[blockIdx.x];
    for (int k = 0; k < wv; ++k) woff += wsum[k];
    int excl = woff + inc - v;
    if (i < NN) { rows[i] = excl; cursor[i] = excl; }
}

// =============== fused scatter + GEMM v6 "16-row waves, max occupancy" ===============
// gemm part: block = 64 rows x 128 cols, 4 waves x 16 rows. A fp32 packed in-kernel,
// B frags from global wT (L2-resident). Swapped MFMA -> direct row-major stores. No LDS.
__global__ __launch_bounds__(256, 4) void gemm6_kernel(
    const float* __restrict__ xf, const u16* __restrict__ wT,
    const float* __restrict__ Wb, const float* __restrict__ Ub, const float* __restrict__ Vb,
    char* __restrict__ WVh, float* __restrict__ Uh,
    const int* __restrict__ src, const int* __restrict__ dst,
    int* __restrict__ cursor, int* __restrict__ esrc) {
    int b = blockIdx.x;
    if (b < SCAT_BLOCKS) {
        int e = b * 256 + threadIdx.x;
        if (e < NE) {
            int d = dst[e];
            int pos = atomicAdd(&cursor[d], 1);
            esrc[pos] = src[e];
        }
        return;
    }
    int gb = b - SCAT_BLOCKS;
    int rb = (gb % GEMM_RB) * 64;
    int cgy = gb / GEMM_RB;               // 0..5
    int cbg = cgy * 128;

    int t = threadIdx.x, lane = t & 63, w = t >> 6;

    // ---- A: 8 fragments (16 rows x 256k) packed from fp32 ----
    int rw = rb + w * 16 + (lane & 15);
    int rwc = min(rw, NN - 1);
    const float* xp = xf + (size_t)rwc * 256 + (lane >> 4) * 8;
    short8 afr[8];
#pragma unroll
    for (int ks = 0; ks < 8; ++ks) {
        floatx4 f0 = *(const floatx4*)(xp + ks * 32);
        floatx4 f1 = *(const floatx4*)(xp + ks * 32 + 4);
        uint4 pk;
        pk.x = pack_bf(f0[0], f0[1]);
        pk.y = pack_bf(f0[2], f0[3]);
        pk.z = pack_bf(f1[0], f1[1]);
        pk.w = pack_bf(f1[2], f1[3]);
        afr[ks] = *(short8*)&pk;
    }

    // ---- compute: 64 global B-frag loads (L2-hot) + 64 MFMA, swapped operands ----
    const u16* wTb = wT + (size_t)(cbg + (lane & 15)) * 256 + (lane >> 4) * 8;
    floatx4 acc[8] = {};
#pragma unroll
    for (int ks = 0; ks < 8; ++ks) {
#pragma unroll
        for (int cf = 0; cf < 8; ++cf) {
            short8 bfrag = *(const short8*)(wTb + (size_t)cf * 16 * 256 + ks * 32);
            acc[cf] = __builtin_amdgcn_mfma_f32_16x16x32_bf16(bfrag, afr[ks], acc[cf], 0, 0, 0);
        }
    }

    // ---- epilogue: direct stores; lane holds 4 consecutive channels per fragment ----
    if (rw >= NN) return;
    int g = cgy >> 1;                    // 0 -> Wh, 1 -> Uh, 2 -> Vh
    int cloc = (cgy & 1) * 128;
    const float* bias = (g == 0) ? Wb : ((g == 1) ? Ub : Vb);

#pragma unroll
    for (int cf = 0; cf < 8; ++cf) {
        int colc = cloc + cf * 16 + (lane >> 4) * 4;
        floatx4 bv = *(const floatx4*)(bias + colc);
        float v0 = acc[cf][0] + bv[0];
        float v1 = acc[cf][1] + bv[1];
        float v2 = acc[cf][2] + bv[2];
        float v3 = acc[cf][3] + bv[3];
        if (g == 1) {
            floatx4 o = { v0, v1, v2, v3 };
            *(floatx4*)(Uh + (size_t)rw * 256 + colc) = o;
        } else if (g == 0) {
#if HAVE_FP8
            u32 p = 0;
            p = __builtin_amdgcn_cvt_pk_fp8_f32(v0, v1, p, false);
            p = __builtin_amdgcn_cvt_pk_fp8_f32(v2, v3, p, true);
            *(u32*)(WVh + (size_t)rw * ROWB + colc) = p;
#else
            uint2 o = { pack_bf(v0, v1), pack_bf(v2, v3) };
            *(uint2*)(WVh + (size_t)rw * ROWB + colc * 2) = o;
#endif
        } else {
#if HAVE_FP8
            uint2 o = { pack_bf(v0, v1), pack_bf(v2, v3) };
            *(uint2*)(WVh + (size_t)rw * ROWB + 256 + colc * 2) = o;
#else
            uint2 o = { pack_bf(v0, v1), pack_bf(v2, v3) };
            *(uint2*)(WVh + (size_t)rw * ROWB + 512 + colc * 2) = o;
#endif
        }
    }
}

// ---------------- node-centric aggregate + LN + ReLU + residual ----------------
__global__ __launch_bounds__(256) void node_kernel(
    const char* __restrict__ WVh, const float* __restrict__ x,
    const int* __restrict__ rows, const int* __restrict__ esrc,
    const float* __restrict__ attn_l, const float* __restrict__ attn_r,
    const float* __restrict__ gamma, const float* __restrict__ beta,
    float* inout) {
    int wv = threadIdx.x >> 6, lane = threadIdx.x & 63;
    int v = blockIdx.x * 4 + wv;
    if (v >= NN) return;
    int c0 = lane * 4;

    const float NL2E = -1.44269504f;    // -log2(e)
    floatx4 alv = *(const floatx4*)(attn_l + c0);
    floatx4 arv = *(const floatx4*)(attn_r + c0);

    float mywf[4];
#if HAVE_FP8
    {
        u32 myw = *(const u32*)(WVh + (size_t)v * ROWB + lane * 4);
        floatx2 a = __builtin_amdgcn_cvt_pk_f32_fp8(myw, false);
        floatx2 b = __builtin_amdgcn_cvt_pk_f32_fp8(myw, true);
        mywf[0] = a[0]; mywf[1] = a[1]; mywf[2] = b[0]; mywf[3] = b[1];
    }
#else
    {
        uint2 myw = *(const uint2*)(WVh + (size_t)v * ROWB + lane * 8);
        mywf[0] = bf_lo(myw.x); mywf[1] = bf_hi(myw.x);
        mywf[2] = bf_lo(myw.y); mywf[3] = bf_hi(myw.y);
    }
#endif
    float al2[4] = { alv[0] * NL2E, alv[1] * NL2E, alv[2] * NL2E, alv[3] * NL2E };
    float td2[4] = { mywf[0] * arv[0] * NL2E, mywf[1] * arv[1] * NL2E,
                     mywf[2] * arv[2] * NL2E, mywf[3] * arv[3] * NL2E };

    float acc_h[4] = {0.f, 0.f, 0.f, 0.f};
    float acc_s[4] = {0.f, 0.f, 0.f, 0.f};

#if HAVE_FP8
    auto edge = [&](u32 w8, uint2 vu) {
        floatx2 a = __builtin_amdgcn_cvt_pk_f32_fp8(w8, false);
        floatx2 b = __builtin_amdgcn_cvt_pk_f32_fp8(w8, true);
        float wf[4] = { a[0], a[1], b[0], b[1] };
        float vf[4] = { bf_lo(vu.x), bf_hi(vu.x), bf_lo(vu.y), bf_hi(vu.y) };
#pragma unroll
        for (int j = 0; j < 4; ++j) {
            float m = fmaf(wf[j], al2[j], td2[j]);
            float s = __builtin_amdgcn_rcpf(1.0f + EXP2F(m));
            acc_s[j] += s;
            acc_h[j] = fmaf(s, vf[j], acc_h[j]);
        }
    };
    int e = rows[v], e1 = rows[v + 1];
    for (; e + 8 <= e1; e += 8) {
        int us[8];
#pragma unroll
        for (int q = 0; q < 8; ++q) us[q] = esrc[e + q];
        u32 w8[8]; uint2 vu[8];
#pragma unroll
        for (int q = 0; q < 8; ++q) {
            const char* p = WVh + (size_t)us[q] * ROWB;
            w8[q] = *(const u32*)(p + lane * 4);
            vu[q] = *(const uint2*)(p + 256 + lane * 8);
        }
#pragma unroll
        for (int q = 0; q < 8; ++q) edge(w8[q], vu[q]);
    }
    for (; e < e1; ++e) {
        const char* p = WVh + (size_t)esrc[e] * ROWB;
        edge(*(const u32*)(p + lane * 4), *(const uint2*)(p + 256 + lane * 8));
    }
#else
    auto edge = [&](uint2 wu, uint2 vu) {
        float wf[4] = { bf_lo(wu.x), bf_hi(wu.x), bf_lo(wu.y), bf_hi(wu.y) };
        float vf[4] = { bf_lo(vu.x), bf_hi(vu.x), bf_lo(vu.y), bf_hi(vu.y) };
#pragma unroll
        for (int j = 0; j < 4; ++j) {
            float m = fmaf(wf[j], al2[j], td2[j]);
            float s = __builtin_amdgcn_rcpf(1.0f + EXP2F(m));
            acc_s[j] += s;
            acc_h[j] = fmaf(s, vf[j], acc_h[j]);
        }
    };
    int e = rows[v], e1 = rows[v + 1];
    for (; e + 8 <= e1; e += 8) {
        int us[8];
#pragma unroll
        for (int q = 0; q < 8; ++q) us[q] = esrc[e + q];
        uint2 wu[8], vu[8];
#pragma unroll
        for (int q = 0; q < 8; ++q) {
            const char* p = WVh + (size_t)us[q] * ROWB;
            wu[q] = *(const uint2*)(p + lane * 8);
            vu[q] = *(const uint2*)(p + 512 + lane * 8);
        }
#pragma unroll
        for (int q = 0; q < 8; ++q) edge(wu[q], vu[q]);
    }
    for (; e < e1; ++e) {
        const char* p = WVh + (size_t)esrc[e] * ROWB;
        edge(*(const uint2*)(p + lane * 8), *(const uint2*)(p + 512 + lane * 8));
    }
#endif

    floatx4 uh = *(const floatx4*)(inout + (size_t)v * 256 + c0);
    float h[4];
#pragma unroll
    for (int j = 0; j < 4; ++j)
        h[j] = uh[j] + acc_h[j] * __builtin_amdgcn_rcpf(acc_s[j] + 1e-6f);

    float s01 = h[0] + h[1] + h[2] + h[3];
#pragma unroll
    for (int m = 32; m; m >>= 1) s01 += __shfl_xor(s01, m, 64);
    float mu = s01 * (1.0f / 256.0f);
    float d[4] = { h[0] - mu, h[1] - mu, h[2] - mu, h[3] - mu };
    float sq = d[0] * d[0] + d[1] * d[1] + d[2] * d[2] + d[3] * d[3];
#pragma unroll
    for (int m = 32; m; m >>= 1) sq += __shfl_xor(sq, m, 64);
    float inv = rsqrtf(sq * (1.0f / 256.0f) + 1e-6f);

    floatx4 gm = *(const floatx4*)(gamma + c0);
    floatx4 bt = *(const floatx4*)(beta + c0);
    floatx4 xr = *(const floatx4*)(x + (size_t)v * 256 + c0);
    floatx4 res;
#pragma unroll
    for (int j = 0; j < 4; ++j) {
        float y = d[j] * inv * gm[j] + bt[j];
        y = fmaxf(y, 0.0f);
        res[j] = xr[j] + y;
    }
    *(floatx4*)(inout + (size_t)v * 256 + c0) = res;
}

extern "C" void kernel_launch(void* const* d_in, const int* in_sizes, int n_in,
                              void* d_out, int out_size, void* d_ws, size_t ws_size,
                              hipStream_t stream) {
    const float* x       = (const float*)d_in[0];
    const int*   src     = (const int*)d_in[1];
    const int*   dst     = (const int*)d_in[2];
    const float* W_w     = (const float*)d_in[3];
    const float* W_b     = (const float*)d_in[4];
    const float* U_w     = (const float*)d_in[5];
    const float* U_b     = (const float*)d_in[6];
    const float* V_w     = (const float*)d_in[7];
    const float* V_b     = (const float*)d_in[8];
    const float* attn_l  = (const float*)d_in[9];
    const float* attn_r  = (const float*)d_in[10];
    const float* gamma   = (const float*)d_in[11];
    const float* beta    = (const float*)d_in[12];

    char* ws = (char*)d_ws;
    size_t off = 0;
    auto alloc = [&](size_t bytes) -> char* {
        char* p = ws + off;
        off += (bytes + 255) & ~(size_t)255;
        return p;
    };
    char* WVh    = alloc((size_t)NN * ROWB);              // [fp8 Wh | bf16 Vh] per node
    u16* wT      = (u16*)alloc((size_t)768 * 256 * 2);
    int* deg     = (int*)alloc((size_t)NN * 4);
    int* rows    = (int*)alloc((size_t)(NN + 1) * 4);
    int* cursor  = (int*)alloc((size_t)NN * 4);
    int* esrc    = (int*)alloc((size_t)NE * 4);
    int* bsum    = (int*)alloc((size_t)NB * 4);
    int* bpre    = (int*)alloc((size_t)NB * 4);

    float* Uh_f32 = (float*)d_out;   // staged in d_out, overwritten by node_kernel

    hipMemsetAsync(deg, 0, (size_t)NN * 4, stream);

    prep_kernel<<<TW_BLOCKS + HIST_BLOCKS, 256, 0, stream>>>(W_w, U_w, V_w, wT, dst, deg);

    scanA_kernel<<<NB, 256, 0, stream>>>(deg, bsum);
    scanB_kernel<<<1, 256, 0, stream>>>(bsum, bpre, rows + NN);
    scanC_kernel<<<NB, 256, 0, stream>>>(deg, bpre, rows, cursor);

    gemm6_kernel<<<SCAT_BLOCKS + GEMM_BLOCKS, 256, 0, stream>>>(
        x, wT, W_b, U_b, V_b, WVh, Uh_f32, src, dst, cursor, esrc);

    node_kernel<<<(NN + 3) / 4, 256, 0, stream>>>(
        WVh, x, rows, esrc, attn_l, attn_r, gamma, beta, (float*)d_out);
}

// Round 11
// 315.921 us; speedup vs baseline: 1.2020x; 1.2020x over previous
//
#include <hip/hip_runtime.h>
#include <hip/hip_bf16.h>

#define NN 50000
#define NE 800000
#define NB 196          // ceil(NN/256)
#define NROWPAD 50048   // 391*128, so GEMM A reads stay in-bounds

#define XCVT_BLOCKS 6250    // NN*256/8/256
#define TW_BLOCKS   192     // 8*8*3
#define HIST_BLOCKS 3125    // ceil(NE/256)
#define GEMM_NWG    2346    // 391 * 6

#if __has_builtin(__builtin_amdgcn_cvt_pk_fp8_f32) && __has_builtin(__builtin_amdgcn_cvt_pk_f32_fp8)
#define HAVE_FP8 1
#define ROWB 768            // 256B fp8 Wh | 512B bf16 Vh
#else
#define HAVE_FP8 0
#define ROWB 1024           // 512B bf16 Wh | 512B bf16 Vh
#endif

typedef __attribute__((ext_vector_type(8))) short short8;
typedef __attribute__((ext_vector_type(4))) float floatx4;
typedef __attribute__((ext_vector_type(2))) float floatx2;
typedef unsigned short u16;
typedef unsigned int u32;

__device__ __forceinline__ u16 f2bf(float f) {
    u32 u = __float_as_uint(f);
    u += 0x7FFFu + ((u >> 16) & 1u);   // RNE
    return (u16)(u >> 16);
}
__device__ __forceinline__ float bf_lo(u32 u) { return __uint_as_float(u << 16); }
__device__ __forceinline__ float bf_hi(u32 u) { return __uint_as_float(u & 0xFFFF0000u); }
__device__ __forceinline__ u32 pack_bf(float lo, float hi) {
    return (u32)f2bf(lo) | ((u32)f2bf(hi) << 16);
}

#if __has_builtin(__builtin_amdgcn_exp2f)
#define EXP2F(x) __builtin_amdgcn_exp2f(x)
#else
#define EXP2F(x) exp2f(x)
#endif

// =============== prep: xcvt (x->bf16) + W/U/V transpose + degree histogram ===============
__global__ __launch_bounds__(256) void prep_kernel(
    const float* __restrict__ x, u16* __restrict__ xbf,
    const float* __restrict__ W, const float* __restrict__ U, const float* __restrict__ V,
    u16* __restrict__ wT, const int* __restrict__ dst, int* __restrict__ deg, int do_xcvt) {
    __shared__ float s[32][33];
    int b = blockIdx.x;
    int xb = do_xcvt ? XCVT_BLOCKS : 0;
    if (b < xb) {
        size_t i = ((size_t)b * 256 + threadIdx.x) * 8;
        floatx4 f0 = *(const floatx4*)(x + i);
        floatx4 f1 = *(const floatx4*)(x + i + 4);
        uint4 pk;
        pk.x = pack_bf(f0[0], f0[1]);
        pk.y = pack_bf(f0[2], f0[3]);
        pk.z = pack_bf(f1[0], f1[1]);
        pk.w = pack_bf(f1[2], f1[3]);
        *(uint4*)(xbf + i) = pk;
    } else if (b < xb + TW_BLOCKS) {
        int bb = b - xb;
        int g = bb >> 6, rem = bb & 63;
        int r0 = (rem & 7) * 32, c0 = (rem >> 3) * 32;
        const float* M = (g == 0) ? W : ((g == 1) ? U : V);
        int tx = threadIdx.x & 31, ty = threadIdx.x >> 5;   // 32 x 8
#pragma unroll
        for (int k = 0; k < 4; ++k)
            s[ty + k * 8][tx] = M[(size_t)(r0 + ty + k * 8) * 256 + c0 + tx];
        __syncthreads();
#pragma unroll
        for (int k = 0; k < 4; ++k)
            wT[(size_t)(g * 256 + c0 + ty + k * 8) * 256 + r0 + tx] = f2bf(s[tx][ty + k * 8]);
    } else {
        int e = (b - xb - TW_BLOCKS) * 256 + threadIdx.x;
        if (e < NE) atomicAdd(&deg[dst[e]], 1);
    }
}

// ---------------- 3-phase scan ----------------
__global__ __launch_bounds__(256) void scanA_kernel(const int* __restrict__ deg, int* __restrict__ bsum) {
    int t = threadIdx.x;
    int i = blockIdx.x * 256 + t;
    int v = (i < NN) ? deg[i] : 0;
#pragma unroll
    for (int m = 32; m; m >>= 1) v += __shfl_xor(v, m, 64);
    __shared__ int ws[4];
    if ((t & 63) == 0) ws[t >> 6] = v;
    __syncthreads();
    if (t == 0) bsum[blockIdx.x] = ws[0] + ws[1] + ws[2] + ws[3];
}

__global__ __launch_bounds__(256) void scanB_kernel(const int* __restrict__ bsum, int* __restrict__ bpre,
                                                    int* __restrict__ rows_end) {
    int t = threadIdx.x, lane = t & 63, wv = t >> 6;
    int v = (t < NB) ? bsum[t] : 0;
    int inc = v;
#pragma unroll
    for (int off = 1; off < 64; off <<= 1) {
        int u = __shfl_up(inc, off, 64);
        if (lane >= off) inc += u;
    }
    __shared__ int wsum[4];
    if (lane == 63) wsum[wv] = inc;
    __syncthreads();
    int woff = 0;
    for (int k = 0; k < wv; ++k) woff += wsum[k];
    if (t < NB) bpre[t] = woff + inc - v;
    if (t == 255) rows_end[0] = woff + inc;
}

__global__ __launch_bounds__(256) void scanC_kernel(const int* __restrict__ deg, const int* __restrict__ bpre,
                                                    int* __restrict__ rows, int* __restrict__ cursor) {
    int t = threadIdx.x, lane = t & 63, wv = t >> 6;
    int i = blockIdx.x * 256 + t;
    int v = (i < NN) ? deg[i] : 0;
    int inc = v;
#pragma unroll
    for (int off = 1; off < 64; off <<= 1) {
        int u = __shfl_up(inc, off, 64);
        if (lane >= off) inc += u;
    }
    __shared__ int wsum[4];
    if (lane == 63) wsum[wv] = inc;
    __syncthreads();
    int woff = bpre[blockIdx.x];
    for (int k = 0; k < wv; ++k) woff += wsum[k];
    int excl = woff + inc - v;
    if (i < NN) { rows[i] = excl; cursor[i] = excl; }
}

// ---------------- scatter edges into CSR-by-dst ----------------
__global__ void scatter_kernel(const int* __restrict__ src, const int* __restrict__ dst,
                               int* __restrict__ cursor, int* __restrict__ esrc) {
    int e = blockIdx.x * 256 + threadIdx.x;
    if (e < NE) {
        int d = dst[e];
        int pos = atomicAdd(&cursor[d], 1);
        esrc[pos] = src[e];
    }
}

// =============== GEMM v7: regB + swapped MFMA + explicit ping-pong B batches ===============
// block = 128 rows x 128 cols; wave w owns rows [w*32, w*32+32). B frags from global wT (L2).
// Per k-step: load next 8 B-frags into the idle batch while 16 MFMAs consume the current one.
template<bool USE_BF>
__global__ __launch_bounds__(256, 2) void gemm3_kernel(
    const u16* __restrict__ xbf, const float* __restrict__ xf, const u16* __restrict__ wT,
    const float* __restrict__ Wb, const float* __restrict__ Ub, const float* __restrict__ Vb,
    char* __restrict__ WVh, float* __restrict__ Uh) {
    // XCD-bijective swizzle: q=2346/8=293, r=2
    int orig = blockIdx.x;
    int xcd = orig & 7, j = orig >> 3;
    int wgid = (xcd < 2 ? xcd * 294 : 2 * 294 + (xcd - 2) * 293) + j;
    int rb = (wgid / 6) * 128;
    int cgy = wgid % 6;                   // 0..5, 128 cols each
    int cbg = cgy * 128;

    int t = threadIdx.x, lane = t & 63, w = t >> 6;

    // ---- A: 16 fragments (2 row-groups x 8 k-steps) straight to VGPRs ----
    int arow = rb + w * 32 + (lane & 15);
    short8 afr[2][8];
    if (USE_BF) {
#pragma unroll
        for (int rg = 0; rg < 2; ++rg)
#pragma unroll
            for (int ks = 0; ks < 8; ++ks)
                afr[rg][ks] = *(const short8*)(xbf + (size_t)(arow + rg * 16) * 256 + ks * 32 + (lane >> 4) * 8);
    } else {
#pragma unroll
        for (int rg = 0; rg < 2; ++rg)
#pragma unroll
            for (int ks = 0; ks < 8; ++ks) {
                int row = arow + rg * 16;
                const float* p = xf + ((size_t)(row < NN ? row : 0)) * 256 + ks * 32 + (lane >> 4) * 8;
                floatx4 f0 = *(const floatx4*)(p);
                floatx4 f1 = *(const floatx4*)(p + 4);
                uint4 pk;
                pk.x = pack_bf(f0[0], f0[1]);
                pk.y = pack_bf(f0[2], f0[3]);
                pk.z = pack_bf(f1[0], f1[1]);
                pk.w = pack_bf(f1[2], f1[3]);
                afr[rg][ks] = *(short8*)&pk;
            }
    }

    // ---- compute: ping-pong B batches (8 frags each), 16 MFMA per k-step ----
    const u16* wTb = wT + (size_t)(cbg + (lane & 15)) * 256 + (lane >> 4) * 8;
    floatx4 acc[2][8] = {};
    short8 bfA[8], bfB[8];
#pragma unroll
    for (int cf = 0; cf < 8; ++cf)
        bfA[cf] = *(const short8*)(wTb + (size_t)cf * 16 * 256);
#pragma unroll
    for (int ks = 0; ks < 8; ++ks) {
        if (ks & 1) {
            if (ks < 7) {
#pragma unroll
                for (int cf = 0; cf < 8; ++cf)
                    bfA[cf] = *(const short8*)(wTb + (size_t)cf * 16 * 256 + (ks + 1) * 32);
            }
#pragma unroll
            for (int cf = 0; cf < 8; ++cf) {
                acc[0][cf] = __builtin_amdgcn_mfma_f32_16x16x32_bf16(bfB[cf], afr[0][ks], acc[0][cf], 0, 0, 0);
                acc[1][cf] = __builtin_amdgcn_mfma_f32_16x16x32_bf16(bfB[cf], afr[1][ks], acc[1][cf], 0, 0, 0);
            }
        } else {
#pragma unroll
            for (int cf = 0; cf < 8; ++cf)
                bfB[cf] = *(const short8*)(wTb + (size_t)cf * 16 * 256 + (ks + 1) * 32);
#pragma unroll
            for (int cf = 0; cf < 8; ++cf) {
                acc[0][cf] = __builtin_amdgcn_mfma_f32_16x16x32_bf16(bfA[cf], afr[0][ks], acc[0][cf], 0, 0, 0);
                acc[1][cf] = __builtin_amdgcn_mfma_f32_16x16x32_bf16(bfA[cf], afr[1][ks], acc[1][cf], 0, 0, 0);
            }
        }
    }

    // ---- epilogue: direct stores, 4 consecutive channels per lane per fragment ----
    int g = cgy >> 1;                    // 0 -> Wh, 1 -> Uh, 2 -> Vh
    int cloc = (cgy & 1) * 128;          // 0 or 128
    const float* bias = (g == 0) ? Wb : ((g == 1) ? Ub : Vb);

#pragma unroll
    for (int rg = 0; rg < 2; ++rg) {
        int noderow = rb + w * 32 + rg * 16 + (lane & 15);
        if (noderow >= NN) continue;
#pragma unroll
        for (int cf = 0; cf < 8; ++cf) {
            int colc = cloc + cf * 16 + (lane >> 4) * 4;   // 4 consecutive channels
            floatx4 bv = *(const floatx4*)(bias + colc);
            float v0 = acc[rg][cf][0] + bv[0];
            float v1 = acc[rg][cf][1] + bv[1];
            float v2 = acc[rg][cf][2] + bv[2];
            float v3 = acc[rg][cf][3] + bv[3];
            if (g == 1) {
                floatx4 o = { v0, v1, v2, v3 };
                *(floatx4*)(Uh + (size_t)noderow * 256 + colc) = o;
            } else if (g == 0) {
#if HAVE_FP8
                u32 p = 0;
                p = __builtin_amdgcn_cvt_pk_fp8_f32(v0, v1, p, false);
                p = __builtin_amdgcn_cvt_pk_fp8_f32(v2, v3, p, true);
                *(u32*)(WVh + (size_t)noderow * ROWB + colc) = p;
#else
                uint2 o = { pack_bf(v0, v1), pack_bf(v2, v3) };
                *(uint2*)(WVh + (size_t)noderow * ROWB + colc * 2) = o;
#endif
            } else {
#if HAVE_FP8
                uint2 o = { pack_bf(v0, v1), pack_bf(v2, v3) };
                *(uint2*)(WVh + (size_t)noderow * ROWB + 256 + colc * 2) = o;
#else
                uint2 o = { pack_bf(v0, v1), pack_bf(v2, v3) };
                *(uint2*)(WVh + (size_t)noderow * ROWB + 512 + colc * 2) = o;
#endif
            }
        }
    }
}

// ---------------- node-centric aggregate + LN + ReLU + residual ----------------
__global__ __launch_bounds__(256) void node_kernel(
    const char* __restrict__ WVh, const float* __restrict__ x,
    const int* __restrict__ rows, const int* __restrict__ esrc,
    const float* __restrict__ attn_l, const float* __restrict__ attn_r,
    const float* __restrict__ gamma, const float* __restrict__ beta,
    float* inout) {
    int wv = threadIdx.x >> 6, lane = threadIdx.x & 63;
    int v = blockIdx.x * 4 + wv;
    if (v >= NN) return;
    int c0 = lane * 4;

    const float NL2E = -1.44269504f;    // -log2(e)
    floatx4 alv = *(const floatx4*)(attn_l + c0);
    floatx4 arv = *(const floatx4*)(attn_r + c0);

    float mywf[4];
#if HAVE_FP8
    {
        u32 myw = *(const u32*)(WVh + (size_t)v * ROWB + lane * 4);
        floatx2 a = __builtin_amdgcn_cvt_pk_f32_fp8(myw, false);
        floatx2 b = __builtin_amdgcn_cvt_pk_f32_fp8(myw, true);
        mywf[0] = a[0]; mywf[1] = a[1]; mywf[2] = b[0]; mywf[3] = b[1];
    }
#else
    {
        uint2 myw = *(const uint2*)(WVh + (size_t)v * ROWB + lane * 8);
        mywf[0] = bf_lo(myw.x); mywf[1] = bf_hi(myw.x);
        mywf[2] = bf_lo(myw.y); mywf[3] = bf_hi(myw.y);
    }
#endif
    float al2[4] = { alv[0] * NL2E, alv[1] * NL2E, alv[2] * NL2E, alv[3] * NL2E };
    float td2[4] = { mywf[0] * arv[0] * NL2E, mywf[1] * arv[1] * NL2E,
                     mywf[2] * arv[2] * NL2E, mywf[3] * arv[3] * NL2E };

    float acc_h[4] = {0.f, 0.f, 0.f, 0.f};
    float acc_s[4] = {0.f, 0.f, 0.f, 0.f};

#if HAVE_FP8
    auto edge = [&](u32 w8, uint2 vu) {
        floatx2 a = __builtin_amdgcn_cvt_pk_f32_fp8(w8, false);
        floatx2 b = __builtin_amdgcn_cvt_pk_f32_fp8(w8, true);
        float wf[4] = { a[0], a[1], b[0], b[1] };
        float vf[4] = { bf_lo(vu.x), bf_hi(vu.x), bf_lo(vu.y), bf_hi(vu.y) };
#pragma unroll
        for (int j = 0; j < 4; ++j) {
            float m = fmaf(wf[j], al2[j], td2[j]);
            float s = __builtin_amdgcn_rcpf(1.0f + EXP2F(m));
            acc_s[j] += s;
            acc_h[j] = fmaf(s, vf[j], acc_h[j]);
        }
    };
    int e = rows[v], e1 = rows[v + 1];
    for (; e + 8 <= e1; e += 8) {
        int us[8];
#pragma unroll
        for (int q = 0; q < 8; ++q) us[q] = esrc[e + q];
        u32 w8[8]; uint2 vu[8];
#pragma unroll
        for (int q = 0; q < 8; ++q) {
            const char* p = WVh + (size_t)us[q] * ROWB;
            w8[q] = *(const u32*)(p + lane * 4);
            vu[q] = *(const uint2*)(p + 256 + lane * 8);
        }
#pragma unroll
        for (int q = 0; q < 8; ++q) edge(w8[q], vu[q]);
    }
    for (; e < e1; ++e) {
        const char* p = WVh + (size_t)esrc[e] * ROWB;
        edge(*(const u32*)(p + lane * 4), *(const uint2*)(p + 256 + lane * 8));
    }
#else
    auto edge = [&](uint2 wu, uint2 vu) {
        float wf[4] = { bf_lo(wu.x), bf_hi(wu.x), bf_lo(wu.y), bf_hi(wu.y) };
        float vf[4] = { bf_lo(vu.x), bf_hi(vu.x), bf_lo(vu.y), bf_hi(vu.y) };
#pragma unroll
        for (int j = 0; j < 4; ++j) {
            float m = fmaf(wf[j], al2[j], td2[j]);
            float s = __builtin_amdgcn_rcpf(1.0f + EXP2F(m));
            acc_s[j] += s;
            acc_h[j] = fmaf(s, vf[j], acc_h[j]);
        }
    };
    int e = rows[v], e1 = rows[v + 1];
    for (; e + 8 <= e1; e += 8) {
        int us[8];
#pragma unroll
        for (int q = 0; q < 8; ++q) us[q] = esrc[e + q];
        uint2 wu[8], vu[8];
#pragma unroll
        for (int q = 0; q < 8; ++q) {
            const char* p = WVh + (size_t)us[q] * ROWB;
            wu[q] = *(const uint2*)(p + lane * 8);
            vu[q] = *(const uint2*)(p + 512 + lane * 8);
        }
#pragma unroll
        for (int q = 0; q < 8; ++q) edge(wu[q], vu[q]);
    }
    for (; e < e1; ++e) {
        const char* p = WVh + (size_t)esrc[e] * ROWB;
        edge(*(const uint2*)(p + lane * 8), *(const uint2*)(p + 512 + lane * 8));
    }
#endif

    floatx4 uh = *(const floatx4*)(inout + (size_t)v * 256 + c0);
    float h[4];
#pragma unroll
    for (int j = 0; j < 4; ++j)
        h[j] = uh[j] + acc_h[j] * __builtin_amdgcn_rcpf(acc_s[j] + 1e-6f);

    float s01 = h[0] + h[1] + h[2] + h[3];
#pragma unroll
    for (int m = 32; m; m >>= 1) s01 += __shfl_xor(s01, m, 64);
    float mu = s01 * (1.0f / 256.0f);
    float d[4] = { h[0] - mu, h[1] - mu, h[2] - mu, h[3] - mu };
    float sq = d[0] * d[0] + d[1] * d[1] + d[2] * d[2] + d[3] * d[3];
#pragma unroll
    for (int m = 32; m; m >>= 1) sq += __shfl_xor(sq, m, 64);
    float inv = rsqrtf(sq * (1.0f / 256.0f) + 1e-6f);

    floatx4 gm = *(const floatx4*)(gamma + c0);
    floatx4 bt = *(const floatx4*)(beta + c0);
    floatx4 xr = *(const floatx4*)(x + (size_t)v * 256 + c0);
    floatx4 res;
#pragma unroll
    for (int j = 0; j < 4; ++j) {
        float y = d[j] * inv * gm[j] + bt[j];
        y = fmaxf(y, 0.0f);
        res[j] = xr[j] + y;
    }
    *(floatx4*)(inout + (size_t)v * 256 + c0) = res;
}

extern "C" void kernel_launch(void* const* d_in, const int* in_sizes, int n_in,
                              void* d_out, int out_size, void* d_ws, size_t ws_size,
                              hipStream_t stream) {
    const float* x       = (const float*)d_in[0];
    const int*   src     = (const int*)d_in[1];
    const int*   dst     = (const int*)d_in[2];
    const float* W_w     = (const float*)d_in[3];
    const float* W_b     = (const float*)d_in[4];
    const float* U_w     = (const float*)d_in[5];
    const float* U_b     = (const float*)d_in[6];
    const float* V_w     = (const float*)d_in[7];
    const float* V_b     = (const float*)d_in[8];
    const float* attn_l  = (const float*)d_in[9];
    const float* attn_r  = (const float*)d_in[10];
    const float* gamma   = (const float*)d_in[11];
    const float* beta    = (const float*)d_in[12];

    char* ws = (char*)d_ws;
    size_t off = 0;
    auto alloc = [&](size_t bytes) -> char* {
        char* p = ws + off;
        off += (bytes + 255) & ~(size_t)255;
        return p;
    };
    char* WVh    = alloc((size_t)NN * ROWB);              // [fp8 Wh | bf16 Vh] per node
    u16* wT      = (u16*)alloc((size_t)768 * 256 * 2);
    int* deg     = (int*)alloc((size_t)NN * 4);
    int* rows    = (int*)alloc((size_t)(NN + 1) * 4);
    int* cursor  = (int*)alloc((size_t)NN * 4);
    int* esrc    = (int*)alloc((size_t)NE * 4);
    int* bsum    = (int*)alloc((size_t)NB * 4);
    int* bpre    = (int*)alloc((size_t)NB * 4);
    u16* xbf     = (u16*)alloc((size_t)NROWPAD * 256 * 2);   // optional (last)
    bool use_bf  = (ws_size >= off);

    float* Uh_f32 = (float*)d_out;   // staged in d_out, overwritten by node_kernel

    hipMemsetAsync(deg, 0, (size_t)NN * 4, stream);

    int xb = use_bf ? XCVT_BLOCKS : 0;
    prep_kernel<<<xb + TW_BLOCKS + HIST_BLOCKS, 256, 0, stream>>>(
        x, xbf, W_w, U_w, V_w, wT, dst, deg, use_bf ? 1 : 0);

    scanA_kernel<<<NB, 256, 0, stream>>>(deg, bsum);
    scanB_kernel<<<1, 256, 0, stream>>>(bsum, bpre, rows + NN);
    scanC_kernel<<<NB, 256, 0, stream>>>(deg, bpre, rows, cursor);
    scatter_kernel<<<(NE + 255) / 256, 256, 0, stream>>>(src, dst, cursor, esrc);

    if (use_bf) {
        gemm3_kernel<true><<<GEMM_NWG, 256, 0, stream>>>(xbf, x, wT, W_b, U_b, V_b, WVh, Uh_f32);
    } else {
        gemm3_kernel<false><<<GEMM_NWG, 256, 0, stream>>>(nullptr, x, wT, W_b, U_b, V_b, WVh, Uh_f32);
    }

    node_kernel<<<(NN + 3) / 4, 256, 0, stream>>>(
        WVh, x, rows, esrc, attn_l, attn_r, gamma, beta, (float*)d_out);
}

// Round 12
// 270.184 us; speedup vs baseline: 1.4055x; 1.1693x over previous
//
#include <hip/hip_runtime.h>
#include <hip/hip_bf16.h>

#define NN 50000
#define NE 800000
#define NB 196          // ceil(NN/256)
#define NROWPAD 50048

#define XCVT_BLOCKS 6250    // NN*256/8/256
#define TW_BLOCKS   192     // 8*8*3
#define HIST_BLOCKS 3125    // ceil(NE/256)

#if __has_builtin(__builtin_amdgcn_cvt_pk_fp8_f32) && __has_builtin(__builtin_amdgcn_cvt_pk_f32_fp8)
#define HAVE_FP8 1
#define ROWB 768            // 256B fp8 Wh | 512B bf16 Vh
#else
#define HAVE_FP8 0
#define ROWB 1024           // 512B bf16 Wh | 512B bf16 Vh
#endif

typedef __attribute__((ext_vector_type(8))) short short8;
typedef __attribute__((ext_vector_type(4))) float floatx4;
typedef __attribute__((ext_vector_type(2))) float floatx2;
typedef unsigned short u16;
typedef unsigned int u32;

__device__ __forceinline__ u16 f2bf(float f) {
    u32 u = __float_as_uint(f);
    u += 0x7FFFu + ((u >> 16) & 1u);   // RNE
    return (u16)(u >> 16);
}
__device__ __forceinline__ float bf_lo(u32 u) { return __uint_as_float(u << 16); }
__device__ __forceinline__ float bf_hi(u32 u) { return __uint_as_float(u & 0xFFFF0000u); }
__device__ __forceinline__ u32 pack_bf(float lo, float hi) {
    return (u32)f2bf(lo) | ((u32)f2bf(hi) << 16);
}
__device__ __forceinline__ void gl_lds16(const void* g, void* l) {
    __builtin_amdgcn_global_load_lds((const __attribute__((address_space(1))) void*)g,
                                     (__attribute__((address_space(3))) void*)l, 16, 0, 0);
}

#if __has_builtin(__builtin_amdgcn_exp2f)
#define EXP2F(x) __builtin_amdgcn_exp2f(x)
#else
#define EXP2F(x) exp2f(x)
#endif

// =============== prep: xcvt (x->bf16) + W/U/V transpose + degree histogram ===============
__global__ __launch_bounds__(256) void prep_kernel(
    const float* __restrict__ x, u16* __restrict__ xbf,
    const float* __restrict__ W, const float* __restrict__ U, const float* __restrict__ V,
    u16* __restrict__ wT, const int* __restrict__ dst, int* __restrict__ deg, int do_xcvt) {
    __shared__ float s[32][33];
    int b = blockIdx.x;
    int xb = do_xcvt ? XCVT_BLOCKS : 0;
    if (b < xb) {
        size_t i = ((size_t)b * 256 + threadIdx.x) * 8;
        floatx4 f0 = *(const floatx4*)(x + i);
        floatx4 f1 = *(const floatx4*)(x + i + 4);
        uint4 pk;
        pk.x = pack_bf(f0[0], f0[1]);
        pk.y = pack_bf(f0[2], f0[3]);
        pk.z = pack_bf(f1[0], f1[1]);
        pk.w = pack_bf(f1[2], f1[3]);
        *(uint4*)(xbf + i) = pk;
    } else if (b < xb + TW_BLOCKS) {
        int bb = b - xb;
        int g = bb >> 6, rem = bb & 63;
        int r0 = (rem & 7) * 32, c0 = (rem >> 3) * 32;
        const float* M = (g == 0) ? W : ((g == 1) ? U : V);
        int tx = threadIdx.x & 31, ty = threadIdx.x >> 5;   // 32 x 8
#pragma unroll
        for (int k = 0; k < 4; ++k)
            s[ty + k * 8][tx] = M[(size_t)(r0 + ty + k * 8) * 256 + c0 + tx];
        __syncthreads();
#pragma unroll
        for (int k = 0; k < 4; ++k)
            wT[(size_t)(g * 256 + c0 + ty + k * 8) * 256 + r0 + tx] = f2bf(s[tx][ty + k * 8]);
    } else {
        int e = (b - xb - TW_BLOCKS) * 256 + threadIdx.x;
        if (e < NE) atomicAdd(&deg[dst[e]], 1);
    }
}

// ---------------- 3-phase scan ----------------
__global__ __launch_bounds__(256) void scanA_kernel(const int* __restrict__ deg, int* __restrict__ bsum) {
    int t = threadIdx.x;
    int i = blockIdx.x * 256 + t;
    int v = (i < NN) ? deg[i] : 0;
#pragma unroll
    for (int m = 32; m; m >>= 1) v += __shfl_xor(v, m, 64);
    __shared__ int ws[4];
    if ((t & 63) == 0) ws[t >> 6] = v;
    __syncthreads();
    if (t == 0) bsum[blockIdx.x] = ws[0] + ws[1] + ws[2] + ws[3];
}

__global__ __launch_bounds__(256) void scanB_kernel(const int* __restrict__ bsum, int* __restrict__ bpre,
                                                    int* __restrict__ rows_end) {
    int t = threadIdx.x, lane = t & 63, wv = t >> 6;
    int v = (t < NB) ? bsum[t] : 0;
    int inc = v;
#pragma unroll
    for (int off = 1; off < 64; off <<= 1) {
        int u = __shfl_up(inc, off, 64);
        if (lane >= off) inc += u;
    }
    __shared__ int wsum[4];
    if (lane == 63) wsum[wv] = inc;
    __syncthreads();
    int woff = 0;
    for (int k = 0; k < wv; ++k) woff += wsum[k];
    if (t < NB) bpre[t] = woff + inc - v;
    if (t == 255) rows_end[0] = woff + inc;
}

__global__ __launch_bounds__(256) void scanC_kernel(const int* __restrict__ deg, const int* __restrict__ bpre,
                                                    int* __restrict__ rows, int* __restrict__ cursor) {
    int t = threadIdx.x, lane = t & 63, wv = t >> 6;
    int i = blockIdx.x * 256 + t;
    int v = (i < NN) ? deg[i] : 0;
    int inc = v;
#pragma unroll
    for (int off = 1; off < 64; off <<= 1) {
        int u = __shfl_up(inc, off, 64);
        if (lane >= off) inc += u;
    }
    __shared__ int wsum[4];
    if (lane == 63) wsum[wv] = inc;
    __syncthreads();
    int woff = bpre[blockIdx.x];
    for (int k = 0; k < wv; ++k) woff += wsum[k];
    int excl = woff + inc - v;
    if (i < NN) { rows[i] = excl; cursor[i] = excl; }
}

// ---------------- scatter edges into CSR-by-dst ----------------
__global__ void scatter_kernel(const int* __restrict__ src, const int* __restrict__ dst,
                               int* __restrict__ cursor, int* __restrict__ esrc) {
    int e = blockIdx.x * 256 + threadIdx.x;
    if (e < NE) {
        int d = dst[e];
        int pos = atomicAdd(&cursor[d], 1);
        esrc[pos] = src[e];
    }
}

// =============== GEMM v8 "max reuse": 256x256 block, full-K B in LDS (128KB), 8 waves ======
// blockIdx.y = pass (0=W,1=U,2=V); each block: B-panel staged ONCE (involutive quad-XOR,
// r5/r6-proven), A full-K in registers, swapped MFMA -> direct row-major stores (r9-proven).
template<bool USE_BF>
__global__ __launch_bounds__(512, 2) void gemm8_kernel(
    const u16* __restrict__ xbf, const float* __restrict__ xf, const u16* __restrict__ wT,
    const float* __restrict__ Wb, const float* __restrict__ Ub, const float* __restrict__ Vb,
    char* __restrict__ WVh, float* __restrict__ Uh) {
    __shared__ __align__(16) u16 Bs[256 * 256];   // 128 KB

    int rb = blockIdx.x * 256;
    int pass = blockIdx.y;                // 0..2 -> W,U,V
    int cbg = pass * 256;

    int t = threadIdx.x, lane = t & 63, w = t >> 6;   // 8 waves

    // ---- stage B: 16 gl_lds16 per wave (128 total = 128KB) ----
#pragma unroll
    for (int i = 0; i < 16; ++i) {
        int slot = w * 16 + i;                       // 0..127, 1KB each = 2 cols
        int ci = slot * 2 + (lane >> 5);
        int q = (lane & 31) ^ (ci & 7);              // involutive source-quad swizzle
        gl_lds16(wT + (size_t)(cbg + ci) * 256 + q * 8, Bs + slot * 512);
    }

    // ---- A: 16 fragments (2 row-groups x 8 k-steps), full K ----
    int arow0 = rb + w * 32 + (lane & 15);
    short8 afr[2][8];
    if (USE_BF) {
#pragma unroll
        for (int rg = 0; rg < 2; ++rg) {
            int row = min(arow0 + rg * 16, NN - 1);
            const u16* p = xbf + (size_t)row * 256 + (lane >> 4) * 8;
#pragma unroll
            for (int ks = 0; ks < 8; ++ks)
                afr[rg][ks] = *(const short8*)(p + ks * 32);
        }
    } else {
#pragma unroll
        for (int rg = 0; rg < 2; ++rg) {
            int row = min(arow0 + rg * 16, NN - 1);
            const float* p = xf + (size_t)row * 256 + (lane >> 4) * 8;
#pragma unroll
            for (int ks = 0; ks < 8; ++ks) {
                floatx4 f0 = *(const floatx4*)(p + ks * 32);
                floatx4 f1 = *(const floatx4*)(p + ks * 32 + 4);
                uint4 pk;
                pk.x = pack_bf(f0[0], f0[1]);
                pk.y = pack_bf(f0[2], f0[3]);
                pk.z = pack_bf(f1[0], f1[1]);
                pk.w = pack_bf(f1[2], f1[3]);
                afr[rg][ks] = *(short8*)&pk;
            }
        }
    }
    __syncthreads();

    // ---- compute: 128 swizzled ds_read_b128 + 256 MFMA per wave ----
    floatx4 acc[2][16] = {};
#pragma unroll
    for (int ks = 0; ks < 8; ++ks) {
#pragma unroll
        for (int cf = 0; cf < 16; ++cf) {
            int ci = cf * 16 + (lane & 15);
            int q = (ks * 4 + (lane >> 4)) ^ (ci & 7);
            short8 bfrag = *(const short8*)(Bs + ci * 256 + q * 8);
            acc[0][cf] = __builtin_amdgcn_mfma_f32_16x16x32_bf16(bfrag, afr[0][ks], acc[0][cf], 0, 0, 0);
            acc[1][cf] = __builtin_amdgcn_mfma_f32_16x16x32_bf16(bfrag, afr[1][ks], acc[1][cf], 0, 0, 0);
        }
    }

    // ---- epilogue: direct stores, 4 consecutive channels per lane per fragment ----
    const float* bias = (pass == 0) ? Wb : ((pass == 1) ? Ub : Vb);
#pragma unroll
    for (int rg = 0; rg < 2; ++rg) {
        int noderow = rb + w * 32 + rg * 16 + (lane & 15);
        if (noderow >= NN) continue;
#pragma unroll
        for (int cf = 0; cf < 16; ++cf) {
            int colc = cf * 16 + (lane >> 4) * 4;    // 4 consecutive channels in [0,256)
            floatx4 bv = *(const floatx4*)(bias + colc);
            float v0 = acc[rg][cf][0] + bv[0];
            float v1 = acc[rg][cf][1] + bv[1];
            float v2 = acc[rg][cf][2] + bv[2];
            float v3 = acc[rg][cf][3] + bv[3];
            if (pass == 1) {
                floatx4 o = { v0, v1, v2, v3 };
                *(floatx4*)(Uh + (size_t)noderow * 256 + colc) = o;
            } else if (pass == 0) {
#if HAVE_FP8
                u32 p = 0;
                p = __builtin_amdgcn_cvt_pk_fp8_f32(v0, v1, p, false);
                p = __builtin_amdgcn_cvt_pk_fp8_f32(v2, v3, p, true);
                *(u32*)(WVh + (size_t)noderow * ROWB + colc) = p;
#else
                uint2 o = { pack_bf(v0, v1), pack_bf(v2, v3) };
                *(uint2*)(WVh + (size_t)noderow * ROWB + colc * 2) = o;
#endif
            } else {
#if HAVE_FP8
                uint2 o = { pack_bf(v0, v1), pack_bf(v2, v3) };
                *(uint2*)(WVh + (size_t)noderow * ROWB + 256 + colc * 2) = o;
#else
                uint2 o = { pack_bf(v0, v1), pack_bf(v2, v3) };
                *(uint2*)(WVh + (size_t)noderow * ROWB + 512 + colc * 2) = o;
#endif
            }
        }
    }
}

// ---------------- node-centric aggregate + LN + ReLU + residual ----------------
__global__ __launch_bounds__(256) void node_kernel(
    const char* __restrict__ WVh, const float* __restrict__ x,
    const int* __restrict__ rows, const int* __restrict__ esrc,
    const float* __restrict__ attn_l, const float* __restrict__ attn_r,
    const float* __restrict__ gamma, const float* __restrict__ beta,
    float* inout) {
    int wv = threadIdx.x >> 6, lane = threadIdx.x & 63;
    int v = blockIdx.x * 4 + wv;
    if (v >= NN) return;
    int c0 = lane * 4;

    const float NL2E = -1.44269504f;    // -log2(e)
    floatx4 alv = *(const floatx4*)(attn_l + c0);
    floatx4 arv = *(const floatx4*)(attn_r + c0);

    float mywf[4];
#if HAVE_FP8
    {
        u32 myw = *(const u32*)(WVh + (size_t)v * ROWB + lane * 4);
        floatx2 a = __builtin_amdgcn_cvt_pk_f32_fp8(myw, false);
        floatx2 b = __builtin_amdgcn_cvt_pk_f32_fp8(myw, true);
        mywf[0] = a[0]; mywf[1] = a[1]; mywf[2] = b[0]; mywf[3] = b[1];
    }
#else
    {
        uint2 myw = *(const uint2*)(WVh + (size_t)v * ROWB + lane * 8);
        mywf[0] = bf_lo(myw.x); mywf[1] = bf_hi(myw.x);
        mywf[2] = bf_lo(myw.y); mywf[3] = bf_hi(myw.y);
    }
#endif
    float al2[4] = { alv[0] * NL2E, alv[1] * NL2E, alv[2] * NL2E, alv[3] * NL2E };
    float td2[4] = { mywf[0] * arv[0] * NL2E, mywf[1] * arv[1] * NL2E,
                     mywf[2] * arv[2] * NL2E, mywf[3] * arv[3] * NL2E };

    float acc_h[4] = {0.f, 0.f, 0.f, 0.f};
    float acc_s[4] = {0.f, 0.f, 0.f, 0.f};

#if HAVE_FP8
    auto edge = [&](u32 w8, uint2 vu) {
        floatx2 a = __builtin_amdgcn_cvt_pk_f32_fp8(w8, false);
        floatx2 b = __builtin_amdgcn_cvt_pk_f32_fp8(w8, true);
        float wf[4] = { a[0], a[1], b[0], b[1] };
        float vf[4] = { bf_lo(vu.x), bf_hi(vu.x), bf_lo(vu.y), bf_hi(vu.y) };
#pragma unroll
        for (int j = 0; j < 4; ++j) {
            float m = fmaf(wf[j], al2[j], td2[j]);
            float s = __builtin_amdgcn_rcpf(1.0f + EXP2F(m));
            acc_s[j] += s;
            acc_h[j] = fmaf(s, vf[j], acc_h[j]);
        }
    };
    int e = rows[v], e1 = rows[v + 1];
    for (; e + 8 <= e1; e += 8) {
        int us[8];
#pragma unroll
        for (int q = 0; q < 8; ++q) us[q] = esrc[e + q];
        u32 w8[8]; uint2 vu[8];
#pragma unroll
        for (int q = 0; q < 8; ++q) {
            const char* p = WVh + (size_t)us[q] * ROWB;
            w8[q] = *(const u32*)(p + lane * 4);
            vu[q] = *(const uint2*)(p + 256 + lane * 8);
        }
#pragma unroll
        for (int q = 0; q < 8; ++q) edge(w8[q], vu[q]);
    }
    for (; e < e1; ++e) {
        const char* p = WVh + (size_t)esrc[e] * ROWB;
        edge(*(const u32*)(p + lane * 4), *(const uint2*)(p + 256 + lane * 8));
    }
#else
    auto edge = [&](uint2 wu, uint2 vu) {
        float wf[4] = { bf_lo(wu.x), bf_hi(wu.x), bf_lo(wu.y), bf_hi(wu.y) };
        float vf[4] = { bf_lo(vu.x), bf_hi(vu.x), bf_lo(vu.y), bf_hi(vu.y) };
#pragma unroll
        for (int j = 0; j < 4; ++j) {
            float m = fmaf(wf[j], al2[j], td2[j]);
            float s = __builtin_amdgcn_rcpf(1.0f + EXP2F(m));
            acc_s[j] += s;
            acc_h[j] = fmaf(s, vf[j], acc_h[j]);
        }
    };
    int e = rows[v], e1 = rows[v + 1];
    for (; e + 8 <= e1; e += 8) {
        int us[8];
#pragma unroll
        for (int q = 0; q < 8; ++q) us[q] = esrc[e + q];
        uint2 wu[8], vu[8];
#pragma unroll
        for (int q = 0; q < 8; ++q) {
            const char* p = WVh + (size_t)us[q] * ROWB;
            wu[q] = *(const uint2*)(p + lane * 8);
            vu[q] = *(const uint2*)(p + 512 + lane * 8);
        }
#pragma unroll
        for (int q = 0; q < 8; ++q) edge(wu[q], vu[q]);
    }
    for (; e < e1; ++e) {
        const char* p = WVh + (size_t)esrc[e] * ROWB;
        edge(*(const uint2*)(p + lane * 8), *(const uint2*)(p + 512 + lane * 8));
    }
#endif

    floatx4 uh = *(const floatx4*)(inout + (size_t)v * 256 + c0);
    float h[4];
#pragma unroll
    for (int j = 0; j < 4; ++j)
        h[j] = uh[j] + acc_h[j] * __builtin_amdgcn_rcpf(acc_s[j] + 1e-6f);

    float s01 = h[0] + h[1] + h[2] + h[3];
#pragma unroll
    for (int m = 32; m; m >>= 1) s01 += __shfl_xor(s01, m, 64);
    float mu = s01 * (1.0f / 256.0f);
    float d[4] = { h[0] - mu, h[1] - mu, h[2] - mu, h[3] - mu };
    float sq = d[0] * d[0] + d[1] * d[1] + d[2] * d[2] + d[3] * d[3];
#pragma unroll
    for (int m = 32; m; m >>= 1) sq += __shfl_xor(sq, m, 64);
    float inv = rsqrtf(sq * (1.0f / 256.0f) + 1e-6f);

    floatx4 gm = *(const floatx4*)(gamma + c0);
    floatx4 bt = *(const floatx4*)(beta + c0);
    floatx4 xr = *(const floatx4*)(x + (size_t)v * 256 + c0);
    floatx4 res;
#pragma unroll
    for (int j = 0; j < 4; ++j) {
        float y = d[j] * inv * gm[j] + bt[j];
        y = fmaxf(y, 0.0f);
        res[j] = xr[j] + y;
    }
    *(floatx4*)(inout + (size_t)v * 256 + c0) = res;
}

extern "C" void kernel_launch(void* const* d_in, const int* in_sizes, int n_in,
                              void* d_out, int out_size, void* d_ws, size_t ws_size,
                              hipStream_t stream) {
    const float* x       = (const float*)d_in[0];
    const int*   src     = (const int*)d_in[1];
    const int*   dst     = (const int*)d_in[2];
    const float* W_w     = (const float*)d_in[3];
    const float* W_b     = (const float*)d_in[4];
    const float* U_w     = (const float*)d_in[5];
    const float* U_b     = (const float*)d_in[6];
    const float* V_w     = (const float*)d_in[7];
    const float* V_b     = (const float*)d_in[8];
    const float* attn_l  = (const float*)d_in[9];
    const float* attn_r  = (const float*)d_in[10];
    const float* gamma   = (const float*)d_in[11];
    const float* beta    = (const float*)d_in[12];

    char* ws = (char*)d_ws;
    size_t off = 0;
    auto alloc = [&](size_t bytes) -> char* {
        char* p = ws + off;
        off += (bytes + 255) & ~(size_t)255;
        return p;
    };
    char* WVh    = alloc((size_t)NN * ROWB);              // [fp8 Wh | bf16 Vh] per node
    u16* wT      = (u16*)alloc((size_t)768 * 256 * 2);
    int* deg     = (int*)alloc((size_t)NN * 4);
    int* rows    = (int*)alloc((size_t)(NN + 1) * 4);
    int* cursor  = (int*)alloc((size_t)NN * 4);
    int* esrc    = (int*)alloc((size_t)NE * 4);
    int* bsum    = (int*)alloc((size_t)NB * 4);
    int* bpre    = (int*)alloc((size_t)NB * 4);
    u16* xbf     = (u16*)alloc((size_t)NROWPAD * 256 * 2);   // optional (last)
    bool use_bf  = (ws_size >= off);

    float* Uh_f32 = (float*)d_out;   // staged in d_out, overwritten by node_kernel

    hipMemsetAsync(deg, 0, (size_t)NN * 4, stream);

    int xb = use_bf ? XCVT_BLOCKS : 0;
    prep_kernel<<<xb + TW_BLOCKS + HIST_BLOCKS, 256, 0, stream>>>(
        x, xbf, W_w, U_w, V_w, wT, dst, deg, use_bf ? 1 : 0);

    scanA_kernel<<<NB, 256, 0, stream>>>(deg, bsum);
    scanB_kernel<<<1, 256, 0, stream>>>(bsum, bpre, rows + NN);
    scanC_kernel<<<NB, 256, 0, stream>>>(deg, bpre, rows, cursor);
    scatter_kernel<<<(NE + 255) / 256, 256, 0, stream>>>(src, dst, cursor, esrc);

    dim3 gg(NB, 3);   // 196 row-blocks x 3 passes (W,U,V)
    if (use_bf) {
        gemm8_kernel<true><<<gg, 512, 0, stream>>>(xbf, x, wT, W_b, U_b, V_b, WVh, Uh_f32);
    } else {
        gemm8_kernel<false><<<gg, 512, 0, stream>>>(nullptr, x, wT, W_b, U_b, V_b, WVh, Uh_f32);
    }

    node_kernel<<<(NN + 3) / 4, 256, 0, stream>>>(
        WVh, x, rows, esrc, attn_l, attn_r, gamma, beta, (float*)d_out);
}